// Round 4
// baseline (798.889 us; speedup 1.0000x reference)
//
#include <hip/hip_runtime.h>
#include <math.h>

#define N_NODES 100000
#define N_EDGES 3200000
// ws floats: dinv N + bufA 16N + bufB 16N, then 1 int flag
#define WS_FLOATS_NEEDED (33u * N_NODES + 16u)

// ---------------------------------------------------------------------------
// dtype probe: edge_index may be int32 or raw int64 (reference uses int64).
// For int64 little-endian values in [0,1e5), every odd 32-bit word == 0.
__global__ void k_detect_i64(const int* __restrict__ ei_words, int* __restrict__ flag) {
    if (blockIdx.x == 0 && threadIdx.x == 0) {
        int allzero = 1;
        for (int i = 0; i < 64; i++)
            if (ei_words[2 * i + 1] != 0) allzero = 0;
        *flag = allzero;  // 1 => int64 layout
    }
}

__device__ __forceinline__ unsigned load_idx(const int* p32, const long long* p64,
                                             int is64, int e) {
    return is64 ? (unsigned)(unsigned long long)p64[e] : (unsigned)p32[e];
}

// ---------------------------------------------------------------------------
// deg init: deg[n] = 1 (self loop)
__global__ __launch_bounds__(256) void k_deg_init(float* __restrict__ deg) {
    int i = blockIdx.x * 256 + threadIdx.x;
    if (i < N_NODES) deg[i] = 1.0f;
}

// deg count: deg[dst[e]] += 1
__global__ __launch_bounds__(256) void k_deg_count(const int* __restrict__ dst32,
                                                   const long long* __restrict__ dst64,
                                                   const int* __restrict__ flag,
                                                   float* __restrict__ deg) {
    int e = blockIdx.x * 256 + threadIdx.x;
    if (e < N_EDGES) {
        unsigned d = load_idx(dst32, dst64, *flag, e);
        if (d < N_NODES) atomicAdd(&deg[d], 1.0f);
    }
}

// dinv[n] = rsqrt(deg[n])  (in place; deg >= 1 always)
__global__ __launch_bounds__(256) void k_rsqrt(float* __restrict__ deg) {
    int i = blockIdx.x * 256 + threadIdx.x;
    if (i < N_NODES) deg[i] = rsqrtf(deg[i]);
}

// ---------------------------------------------------------------------------
// Layer-1 GEMM: xs[n][f] = dinv[n] * sum_k h[n][k] * W[k][f],  128 -> 16
// Also initializes acc = xs (the self-loop contribution).
__global__ __launch_bounds__(256) void k_gemm1(const float* __restrict__ h,
                                               const float* __restrict__ W,
                                               const float* __restrict__ dinv,
                                               float* __restrict__ xs,
                                               float* __restrict__ acc) {
    __shared__ float Wt[16 * 132];   // transposed W, padded row stride 132
    __shared__ float Hs[16 * 132];   // 16 node rows, padded
    int tid = threadIdx.x;
    for (int i = tid; i < 2048; i += 256) {
        int k = i >> 4, f = i & 15;
        Wt[f * 132 + k] = W[i];
    }
    int nodeBase = blockIdx.x * 16;
    for (int i = tid; i < 512; i += 256) {
        int r = i >> 5, c = i & 31;
        float4 v = ((const float4*)(h + (size_t)(nodeBase + r) * 128))[c];
        *((float4*)&Hs[r * 132 + c * 4]) = v;
    }
    __syncthreads();
    int nl = tid >> 4;
    int f  = tid & 15;
    int n  = nodeBase + nl;
    const float* hr = &Hs[nl * 132];
    const float* wr = &Wt[f * 132];
    float s = 0.0f;
#pragma unroll
    for (int k = 0; k < 128; k++) s += hr[k] * wr[k];
    s *= dinv[n];
    xs[n * 16 + f]  = s;
    acc[n * 16 + f] = s;  // self-loop term
}

// Small GEMM (FI -> FO): xs[n][f] = dinv[n]*sum_k x[n][k]*W[k][f]; acc = xs.
template <int FI, int FO>
__global__ __launch_bounds__(256) void k_gemm_small(const float* __restrict__ x,
                                                    const float* __restrict__ W,
                                                    const float* __restrict__ dinv,
                                                    float* __restrict__ xs,
                                                    float* __restrict__ acc) {
    int i = blockIdx.x * 256 + threadIdx.x;
    if (i >= N_NODES * FO) return;
    int n = i / FO, f = i % FO;
    float s = 0.0f;
#pragma unroll
    for (int k = 0; k < FI; k++) s += x[n * FI + k] * W[k * FO + f];
    s *= dinv[n];
    xs[i] = s;
    acc[i] = s;
}

// Edge scatter: acc[dst][f] += xs[src][f], F threads per edge
template <int F>
__global__ __launch_bounds__(256) void k_scatter(const int* __restrict__ src32,
                                                 const long long* __restrict__ src64,
                                                 const int* __restrict__ dst32,
                                                 const long long* __restrict__ dst64,
                                                 const int* __restrict__ flag,
                                                 const float* __restrict__ xs,
                                                 float* __restrict__ acc) {
    long long gid = (long long)blockIdx.x * 256 + threadIdx.x;
    int e = (int)(gid / F), f = (int)(gid % F);
    if (e < N_EDGES) {
        int is64 = *flag;
        unsigned s = load_idx(src32, src64, is64, e);
        unsigned d = load_idx(dst32, dst64, is64, e);
        if (s < N_NODES && d < N_NODES)
            atomicAdd(&acc[d * F + f], xs[s * F + f]);
    }
}

// finish: out[n][f] = tanh(dinv[n]*acc[n][f] + b[f])
template <int F>
__global__ __launch_bounds__(256) void k_finish(const float* __restrict__ acc,
                                                const float* __restrict__ dinv,
                                                const float* __restrict__ b,
                                                float* __restrict__ out) {
    int i = blockIdx.x * 256 + threadIdx.x;
    if (i >= N_NODES * F) return;
    int n = i / F, f = i % F;
    out[i] = tanhf(dinv[n] * acc[i] + b[f]);
}

// final layer: h3 = tanh(dinv*acc3 + b3) (2), out = h3 @ Wc + bc (8)
__global__ __launch_bounds__(256) void k_final(const float* __restrict__ acc3,
                                               const float* __restrict__ dinv,
                                               const float* __restrict__ b3,
                                               const float* __restrict__ Wc,
                                               const float* __restrict__ bc,
                                               float* __restrict__ out,
                                               float* __restrict__ h3out) {
    int n = blockIdx.x * 256 + threadIdx.x;
    if (n >= N_NODES) return;
    float di = dinv[n];
    float a0 = tanhf(di * acc3[2 * n + 0] + b3[0]);
    float a1 = tanhf(di * acc3[2 * n + 1] + b3[1]);
    h3out[2 * n + 0] = a0;
    h3out[2 * n + 1] = a1;
    float v[8];
#pragma unroll
    for (int c = 0; c < 8; c++) v[c] = a0 * Wc[c] + a1 * Wc[8 + c] + bc[c];
    ((float4*)(out + 8 * n))[0] = make_float4(v[0], v[1], v[2], v[3]);
    ((float4*)(out + 8 * n))[1] = make_float4(v[4], v[5], v[6], v[7]);
}

// fallback if ws is too small: deterministic output, clean validation miss
__global__ __launch_bounds__(256) void k_zero_out(float* __restrict__ out, int n) {
    int i = blockIdx.x * 256 + threadIdx.x;
    if (i < n) out[i] = 0.0f;
}

// ---------------------------------------------------------------------------
extern "C" void kernel_launch(void* const* d_in, const int* in_sizes, int n_in,
                              void* d_out, int out_size, void* d_ws, size_t ws_size,
                              hipStream_t stream) {
    float* out = (float*)d_out;               // N*8 then N*2

    if (d_ws == nullptr || ws_size < WS_FLOATS_NEEDED * sizeof(float)) {
        k_zero_out<<<(out_size + 255) / 256, 256, 0, stream>>>(out, out_size);
        return;
    }

    const float* h   = (const float*)d_in[0];
    const void*  ei  = d_in[1];
    const float* W1  = (const float*)d_in[2];
    const float* b1  = (const float*)d_in[3];
    const float* W2  = (const float*)d_in[4];
    const float* b2  = (const float*)d_in[5];
    const float* W3  = (const float*)d_in[6];
    const float* b3  = (const float*)d_in[7];
    const float* Wc  = (const float*)d_in[8];
    const float* bc  = (const float*)d_in[9];

    const int*       src32 = (const int*)ei;
    const int*       dst32 = src32 + N_EDGES;
    const long long* src64 = (const long long*)ei;
    const long long* dst64 = src64 + N_EDGES;

    float* ws   = (float*)d_ws;
    float* dinv = ws;                        // N
    float* bufA = dinv + N_NODES;            // 16N
    float* bufB = bufA + 16 * N_NODES;       // 16N
    int*   flag = (int*)(bufB + 16 * N_NODES);

    float* xs1  = bufA;
    float* acc1 = bufB;
    float* h1   = bufA;          // overwrites xs1 after scatter
    float* xs2  = bufB;                      // 4N
    float* acc2 = bufB + 4 * N_NODES;        // 4N
    float* h2   = bufA;          // overwrites h1
    float* xs3  = bufB;                      // 2N
    float* acc3 = bufB + 2 * N_NODES;        // 2N

    float* h3out = out + 8 * N_NODES;        // N*2

    const int NB_N = (N_NODES + 255) / 256;
    const int NB_E = (N_EDGES + 255) / 256;

    k_detect_i64<<<1, 64, 0, stream>>>(src32, flag);
    k_deg_init<<<NB_N, 256, 0, stream>>>(dinv);
    k_deg_count<<<NB_E, 256, 0, stream>>>(dst32, dst64, flag, dinv);
    k_rsqrt<<<NB_N, 256, 0, stream>>>(dinv);

    // layer 1: 128 -> 16
    k_gemm1<<<N_NODES / 16, 256, 0, stream>>>(h, W1, dinv, xs1, acc1);
    k_scatter<16><<<(int)(((long long)N_EDGES * 16 + 255) / 256), 256, 0, stream>>>(
        src32, src64, dst32, dst64, flag, xs1, acc1);
    k_finish<16><<<(N_NODES * 16 + 255) / 256, 256, 0, stream>>>(acc1, dinv, b1, h1);

    // layer 2: 16 -> 4
    k_gemm_small<16, 4><<<(N_NODES * 4 + 255) / 256, 256, 0, stream>>>(h1, W2, dinv, xs2, acc2);
    k_scatter<4><<<(int)(((long long)N_EDGES * 4 + 255) / 256), 256, 0, stream>>>(
        src32, src64, dst32, dst64, flag, xs2, acc2);
    k_finish<4><<<(N_NODES * 4 + 255) / 256, 256, 0, stream>>>(acc2, dinv, b2, h2);

    // layer 3: 4 -> 2
    k_gemm_small<4, 2><<<(N_NODES * 2 + 255) / 256, 256, 0, stream>>>(h2, W3, dinv, xs3, acc3);
    k_scatter<2><<<(int)(((long long)N_EDGES * 2 + 255) / 256), 256, 0, stream>>>(
        src32, src64, dst32, dst64, flag, xs3, acc3);

    // h3 + classifier
    k_final<<<NB_N, 256, 0, stream>>>(acc3, dinv, b3, Wc, bc, out, h3out);
}

// Round 5
// 680.738 us; speedup vs baseline: 1.1736x; 1.1736x over previous
//
#include <hip/hip_runtime.h>
#include <math.h>

#define N_NODES 100000
#define N_EDGES 3200000
#define NB_BLK  ((N_NODES + 255) / 256)   // 391 blocks for per-node kernels

// CSR path ws (bytes): floats {dinv N, xs 16N, h 16N} + ints {adj E, cnt N,
// rowstart N, cursor N, partials 512, flag 1}
#define CSR_WS_BYTES ((33u*N_NODES + N_EDGES + 3u*N_NODES + 513u) * 4u)
// fallback atomic path (R4): 33N floats + flag
#define ATOMIC_WS_BYTES ((33u*N_NODES + 16u) * 4u)

// ---------------------------------------------------------------------------
// dtype probe: edge_index may be int32 or raw int64. For int64 LE values in
// [0,1e5), every odd 32-bit word == 0.
__global__ void k_detect_i64(const int* __restrict__ ei_words, int* __restrict__ flag) {
    if (blockIdx.x == 0 && threadIdx.x == 0) {
        int allzero = 1;
        for (int i = 0; i < 64; i++)
            if (ei_words[2 * i + 1] != 0) allzero = 0;
        *flag = allzero;  // 1 => int64 layout
    }
}

__device__ __forceinline__ unsigned load_idx(const int* p32, const long long* p64,
                                             int is64, int e) {
    return is64 ? (unsigned)(unsigned long long)p64[e] : (unsigned)p32[e];
}

// ---------------------------------------------------------------------------
__global__ __launch_bounds__(256) void k_zero_int(int* __restrict__ p, int n) {
    int i = blockIdx.x * 256 + threadIdx.x;
    if (i < n) p[i] = 0;
}

// cnt[dst[e]]++
__global__ __launch_bounds__(256) void k_hist(const int* __restrict__ dst32,
                                              const long long* __restrict__ dst64,
                                              const int* __restrict__ flag,
                                              int* __restrict__ cnt) {
    int e = blockIdx.x * 256 + threadIdx.x;
    if (e < N_EDGES) {
        unsigned d = load_idx(dst32, dst64, *flag, e);
        if (d < N_NODES) atomicAdd(&cnt[d], 1);
    }
}

// dinv[n] = rsqrt(cnt[n] + 1)   (+1 = self loop)
__global__ __launch_bounds__(256) void k_dinv(const int* __restrict__ cnt,
                                              float* __restrict__ dinv) {
    int i = blockIdx.x * 256 + threadIdx.x;
    if (i < N_NODES) dinv[i] = rsqrtf((float)cnt[i] + 1.0f);
}

// per-block sum of cnt -> partials[block]
__global__ __launch_bounds__(256) void k_blkred(const int* __restrict__ cnt,
                                                int* __restrict__ partials) {
    int i = blockIdx.x * 256 + threadIdx.x;
    int v = (i < N_NODES) ? cnt[i] : 0;
#pragma unroll
    for (int off = 32; off > 0; off >>= 1) v += __shfl_down(v, off, 64);
    __shared__ int s[4];
    if ((threadIdx.x & 63) == 0) s[threadIdx.x >> 6] = v;
    __syncthreads();
    if (threadIdx.x == 0) partials[blockIdx.x] = s[0] + s[1] + s[2] + s[3];
}

// exclusive scan of partials[nb] in one block (nb <= 512)
__global__ __launch_bounds__(512) void k_scanpart(int* __restrict__ partials, int nb) {
    __shared__ int s[512];
    int t = threadIdx.x;
    s[t] = (t < nb) ? partials[t] : 0;
    __syncthreads();
    for (int off = 1; off < 512; off <<= 1) {
        int v = (t >= off) ? s[t - off] : 0;
        __syncthreads();
        s[t] += v;
        __syncthreads();
    }
    if (t < nb) partials[t] = (t == 0) ? 0 : s[t - 1];
}

// rowstart[i] = blockExclusive(cnt) + partials[block]; cursor = rowstart
__global__ __launch_bounds__(256) void k_rowscan(const int* __restrict__ cnt,
                                                 const int* __restrict__ partials,
                                                 int* __restrict__ rowstart,
                                                 int* __restrict__ cursor) {
    __shared__ int s[256];
    int i = blockIdx.x * 256 + threadIdx.x;
    int t = threadIdx.x;
    s[t] = (i < N_NODES) ? cnt[i] : 0;
    __syncthreads();
    for (int off = 1; off < 256; off <<= 1) {
        int v = (t >= off) ? s[t - off] : 0;
        __syncthreads();
        s[t] += v;
        __syncthreads();
    }
    int excl = ((t == 0) ? 0 : s[t - 1]) + partials[blockIdx.x];
    if (i < N_NODES) { rowstart[i] = excl; cursor[i] = excl; }
}

// adj[cursor[dst]++] = src    (after this, cursor[n] == row end)
__global__ __launch_bounds__(256) void k_fill(const int* __restrict__ src32,
                                              const long long* __restrict__ src64,
                                              const int* __restrict__ dst32,
                                              const long long* __restrict__ dst64,
                                              const int* __restrict__ flag,
                                              int* __restrict__ cursor,
                                              int* __restrict__ adj) {
    int e = blockIdx.x * 256 + threadIdx.x;
    if (e < N_EDGES) {
        int is64 = *flag;
        unsigned s = load_idx(src32, src64, is64, e);
        unsigned d = load_idx(dst32, dst64, is64, e);
        if (s < N_NODES && d < N_NODES) {
            int pos = atomicAdd(&cursor[d], 1);
            adj[pos] = (int)s;
        }
    }
}

// ---------------------------------------------------------------------------
// Layer-1 GEMM: xs[n][f] = dinv[n] * sum_k h[n][k] * W[k][f],  128 -> 16
// (acc may alias xs; atomic fallback passes a distinct acc for self-loop init)
__global__ __launch_bounds__(256) void k_gemm1(const float* __restrict__ h,
                                               const float* __restrict__ W,
                                               const float* __restrict__ dinv,
                                               float* __restrict__ xs,
                                               float* acc) {
    __shared__ float Wt[16 * 132];
    __shared__ float Hs[16 * 132];
    int tid = threadIdx.x;
    for (int i = tid; i < 2048; i += 256) {
        int k = i >> 4, f = i & 15;
        Wt[f * 132 + k] = W[i];
    }
    int nodeBase = blockIdx.x * 16;
    for (int i = tid; i < 512; i += 256) {
        int r = i >> 5, c = i & 31;
        float4 v = ((const float4*)(h + (size_t)(nodeBase + r) * 128))[c];
        *((float4*)&Hs[r * 132 + c * 4]) = v;
    }
    __syncthreads();
    int nl = tid >> 4;
    int f  = tid & 15;
    int n  = nodeBase + nl;
    const float* hr = &Hs[nl * 132];
    const float* wr = &Wt[f * 132];
    float s = 0.0f;
#pragma unroll
    for (int k = 0; k < 128; k++) s += hr[k] * wr[k];
    s *= dinv[n];
    xs[n * 16 + f]  = s;
    acc[n * 16 + f] = s;
}

template <int FI, int FO>
__global__ __launch_bounds__(256) void k_gemm_small(const float* __restrict__ x,
                                                    const float* __restrict__ W,
                                                    const float* __restrict__ dinv,
                                                    float* __restrict__ xs,
                                                    float* acc) {
    int i = blockIdx.x * 256 + threadIdx.x;
    if (i >= N_NODES * FO) return;
    int n = i / FO, f = i % FO;
    float s = 0.0f;
#pragma unroll
    for (int k = 0; k < FI; k++) s += x[n * FI + k] * W[k * FO + f];
    s *= dinv[n];
    xs[i] = s;
    acc[i] = s;
}

// ---------------------------------------------------------------------------
// Pull aggregation, fused finish:  out[n][f] = tanh(dinv[n]*(xs[n][f] +
//   sum_{src in row(n)} xs[src][f]) + b[f])
// NL lanes per node: f = q%F feature, k = q/F neighbor slot (R = NL/F slots).
template <int F, int NL>
__global__ __launch_bounds__(256) void k_pull(const float* __restrict__ xs,
                                              const int* __restrict__ adj,
                                              const int* __restrict__ rowstart,
                                              const int* __restrict__ rowend,
                                              const float* __restrict__ dinv,
                                              const float* __restrict__ b,
                                              float* __restrict__ out) {
    constexpr int R = NL / F;
    int t = threadIdx.x;
    int g = t / NL, q = t % NL;
    int f = q % F,  k = q / F;
    int n = blockIdx.x * (256 / NL) + g;
    if (n >= N_NODES) return;
    int s0 = rowstart[n], e0 = rowend[n];
    float acc = 0.0f;
    for (int j = s0 + k; j < e0; j += R)
        acc += xs[adj[j] * F + f];
#pragma unroll
    for (int off = NL / 2; off >= F; off >>= 1)
        acc += __shfl_xor(acc, off, 64);
    if (k == 0) {
        acc += xs[n * F + f];  // self loop
        out[n * F + f] = tanhf(dinv[n] * acc + b[f]);
    }
}

// Layer-3 pull (F=2, NL=8) fused with h3 write and 2->8 classifier.
__global__ __launch_bounds__(256) void k_pull_final(const float* __restrict__ xs,
                                                    const int* __restrict__ adj,
                                                    const int* __restrict__ rowstart,
                                                    const int* __restrict__ rowend,
                                                    const float* __restrict__ dinv,
                                                    const float* __restrict__ b3,
                                                    const float* __restrict__ Wc,
                                                    const float* __restrict__ bc,
                                                    float* __restrict__ out,
                                                    float* __restrict__ h3out) {
    const int NL = 8;
    int t = threadIdx.x;
    int g = t / NL, q = t % NL;
    int f = q & 1, k = q >> 1;           // F=2, R=4
    int n = blockIdx.x * (256 / NL) + g;
    if (n >= N_NODES) return;
    int s0 = rowstart[n], e0 = rowend[n];
    float acc = 0.0f;
    for (int j = s0 + k; j < e0; j += 4)
        acc += xs[adj[j] * 2 + f];
    acc += __shfl_xor(acc, 4, 64);
    acc += __shfl_xor(acc, 2, 64);
    float a = 0.0f;
    if (q < 2) {
        acc += xs[n * 2 + f];
        a = tanhf(dinv[n] * acc + b3[f]);
        h3out[2 * n + f] = a;
    }
    int wl = t & 63, gb = wl & ~7;
    float a0 = __shfl(a, gb, 64);
    float a1 = __shfl(a, gb + 1, 64);
    out[8 * n + q] = a0 * Wc[q] + a1 * Wc[8 + q] + bc[q];
}

// ---------------------------------------------------------------------------
// Atomic fallback kernels (R4 pipeline, used only if ws is small)
template <int F>
__global__ __launch_bounds__(256) void k_scatter(const int* __restrict__ src32,
                                                 const long long* __restrict__ src64,
                                                 const int* __restrict__ dst32,
                                                 const long long* __restrict__ dst64,
                                                 const int* __restrict__ flag,
                                                 const float* __restrict__ xs,
                                                 float* __restrict__ acc) {
    long long gid = (long long)blockIdx.x * 256 + threadIdx.x;
    int e = (int)(gid / F), f = (int)(gid % F);
    if (e < N_EDGES) {
        int is64 = *flag;
        unsigned s = load_idx(src32, src64, is64, e);
        unsigned d = load_idx(dst32, dst64, is64, e);
        if (s < N_NODES && d < N_NODES)
            atomicAdd(&acc[d * F + f], xs[s * F + f]);
    }
}

__global__ __launch_bounds__(256) void k_deg_init(float* __restrict__ deg) {
    int i = blockIdx.x * 256 + threadIdx.x;
    if (i < N_NODES) deg[i] = 1.0f;
}
__global__ __launch_bounds__(256) void k_deg_count(const int* __restrict__ dst32,
                                                   const long long* __restrict__ dst64,
                                                   const int* __restrict__ flag,
                                                   float* __restrict__ deg) {
    int e = blockIdx.x * 256 + threadIdx.x;
    if (e < N_EDGES) {
        unsigned d = load_idx(dst32, dst64, *flag, e);
        if (d < N_NODES) atomicAdd(&deg[d], 1.0f);
    }
}
__global__ __launch_bounds__(256) void k_rsqrt(float* __restrict__ deg) {
    int i = blockIdx.x * 256 + threadIdx.x;
    if (i < N_NODES) deg[i] = rsqrtf(deg[i]);
}
template <int F>
__global__ __launch_bounds__(256) void k_finish(const float* __restrict__ acc,
                                                const float* __restrict__ dinv,
                                                const float* __restrict__ b,
                                                float* __restrict__ out) {
    int i = blockIdx.x * 256 + threadIdx.x;
    if (i >= N_NODES * F) return;
    int n = i / F, f = i % F;
    out[i] = tanhf(dinv[n] * acc[i] + b[f]);
}
__global__ __launch_bounds__(256) void k_final(const float* __restrict__ acc3,
                                               const float* __restrict__ dinv,
                                               const float* __restrict__ b3,
                                               const float* __restrict__ Wc,
                                               const float* __restrict__ bc,
                                               float* __restrict__ out,
                                               float* __restrict__ h3out) {
    int n = blockIdx.x * 256 + threadIdx.x;
    if (n >= N_NODES) return;
    float di = dinv[n];
    float a0 = tanhf(di * acc3[2 * n + 0] + b3[0]);
    float a1 = tanhf(di * acc3[2 * n + 1] + b3[1]);
    h3out[2 * n + 0] = a0;
    h3out[2 * n + 1] = a1;
#pragma unroll
    for (int c = 0; c < 8; c++)
        out[8 * n + c] = a0 * Wc[c] + a1 * Wc[8 + c] + bc[c];
}
__global__ __launch_bounds__(256) void k_zero_out(float* __restrict__ out, int n) {
    int i = blockIdx.x * 256 + threadIdx.x;
    if (i < n) out[i] = 0.0f;
}

// ---------------------------------------------------------------------------
extern "C" void kernel_launch(void* const* d_in, const int* in_sizes, int n_in,
                              void* d_out, int out_size, void* d_ws, size_t ws_size,
                              hipStream_t stream) {
    float* out = (float*)d_out;
    const float* h   = (const float*)d_in[0];
    const void*  ei  = d_in[1];
    const float* W1  = (const float*)d_in[2];
    const float* b1  = (const float*)d_in[3];
    const float* W2  = (const float*)d_in[4];
    const float* b2  = (const float*)d_in[5];
    const float* W3  = (const float*)d_in[6];
    const float* b3  = (const float*)d_in[7];
    const float* Wc  = (const float*)d_in[8];
    const float* bc  = (const float*)d_in[9];

    const int*       src32 = (const int*)ei;
    const int*       dst32 = src32 + N_EDGES;
    const long long* src64 = (const long long*)ei;
    const long long* dst64 = src64 + N_EDGES;

    float* h3out = out + 8 * N_NODES;
    const int NB_E = (N_EDGES + 255) / 256;

    if (d_ws != nullptr && ws_size >= CSR_WS_BYTES) {
        // ---------------- CSR pull path ----------------
        float* ws      = (float*)d_ws;
        float* dinv    = ws;                         // N
        float* xs      = dinv + N_NODES;             // 16N
        float* hbuf    = xs + 16 * N_NODES;          // 16N
        int*   adj     = (int*)(hbuf + 16 * N_NODES);// E
        int*   cnt     = adj + N_EDGES;              // N
        int*   rowstart= cnt + N_NODES;              // N
        int*   cursor  = rowstart + N_NODES;         // N  (becomes row end)
        int*   partials= cursor + N_NODES;           // 512
        int*   flag    = partials + 512;             // 1

        k_detect_i64<<<1, 64, 0, stream>>>(src32, flag);
        k_zero_int<<<NB_BLK, 256, 0, stream>>>(cnt, N_NODES);
        k_hist<<<NB_E, 256, 0, stream>>>(dst32, dst64, flag, cnt);
        k_dinv<<<NB_BLK, 256, 0, stream>>>(cnt, dinv);
        k_blkred<<<NB_BLK, 256, 0, stream>>>(cnt, partials);
        k_scanpart<<<1, 512, 0, stream>>>(partials, NB_BLK);
        k_rowscan<<<NB_BLK, 256, 0, stream>>>(cnt, partials, rowstart, cursor);
        k_fill<<<NB_E, 256, 0, stream>>>(src32, src64, dst32, dst64, flag, cursor, adj);

        // layer 1: 128 -> 16
        k_gemm1<<<N_NODES / 16, 256, 0, stream>>>(h, W1, dinv, xs, xs);
        k_pull<16, 16><<<(N_NODES * 16 + 255) / 256, 256, 0, stream>>>(
            xs, adj, rowstart, cursor, dinv, b1, hbuf);
        // layer 2: 16 -> 4
        k_gemm_small<16, 4><<<(N_NODES * 4 + 255) / 256, 256, 0, stream>>>(hbuf, W2, dinv, xs, xs);
        k_pull<4, 8><<<(N_NODES * 8 + 255) / 256, 256, 0, stream>>>(
            xs, adj, rowstart, cursor, dinv, b2, hbuf);
        // layer 3: 4 -> 2, fused classifier
        k_gemm_small<4, 2><<<(N_NODES * 2 + 255) / 256, 256, 0, stream>>>(hbuf, W3, dinv, xs, xs);
        k_pull_final<<<(N_NODES * 8 + 255) / 256, 256, 0, stream>>>(
            xs, adj, rowstart, cursor, dinv, b3, Wc, bc, out, h3out);
        return;
    }

    if (d_ws != nullptr && ws_size >= ATOMIC_WS_BYTES) {
        // ---------------- atomic fallback (R4) ----------------
        float* ws   = (float*)d_ws;
        float* dinv = ws;
        float* bufA = dinv + N_NODES;            // 16N
        float* bufB = bufA + 16 * N_NODES;       // 16N
        int*   flag = (int*)(bufB + 16 * N_NODES);
        float* xs1 = bufA, *acc1 = bufB, *h1 = bufA;
        float* xs2 = bufB, *acc2 = bufB + 4 * N_NODES, *h2 = bufA;
        float* xs3 = bufB, *acc3 = bufB + 2 * N_NODES;

        k_detect_i64<<<1, 64, 0, stream>>>(src32, flag);
        k_deg_init<<<NB_BLK, 256, 0, stream>>>(dinv);
        k_deg_count<<<NB_E, 256, 0, stream>>>(dst32, dst64, flag, dinv);
        k_rsqrt<<<NB_BLK, 256, 0, stream>>>(dinv);
        k_gemm1<<<N_NODES / 16, 256, 0, stream>>>(h, W1, dinv, xs1, acc1);
        k_scatter<16><<<(int)(((long long)N_EDGES * 16 + 255) / 256), 256, 0, stream>>>(
            src32, src64, dst32, dst64, flag, xs1, acc1);
        k_finish<16><<<(N_NODES * 16 + 255) / 256, 256, 0, stream>>>(acc1, dinv, b1, h1);
        k_gemm_small<16, 4><<<(N_NODES * 4 + 255) / 256, 256, 0, stream>>>(h1, W2, dinv, xs2, acc2);
        k_scatter<4><<<(int)(((long long)N_EDGES * 4 + 255) / 256), 256, 0, stream>>>(
            src32, src64, dst32, dst64, flag, xs2, acc2);
        k_finish<4><<<(N_NODES * 4 + 255) / 256, 256, 0, stream>>>(acc2, dinv, b2, h2);
        k_gemm_small<4, 2><<<(N_NODES * 2 + 255) / 256, 256, 0, stream>>>(h2, W3, dinv, xs3, acc3);
        k_scatter<2><<<(int)(((long long)N_EDGES * 2 + 255) / 256), 256, 0, stream>>>(
            src32, src64, dst32, dst64, flag, xs3, acc3);
        k_final<<<NB_BLK, 256, 0, stream>>>(acc3, dinv, b3, Wc, bc, out, h3out);
        return;
    }

    k_zero_out<<<(out_size + 255) / 256, 256, 0, stream>>>(out, out_size);
}

// Round 6
// 350.987 us; speedup vs baseline: 2.2761x; 1.9395x over previous
//
#include <hip/hip_runtime.h>
#include <math.h>

#define N_NODES 100000
#define N_EDGES 3200000
#define NPB    256                               // nodes per bucket
#define NBUCK  ((N_NODES + NPB - 1) / NPB)       // 391
#define NBLKA  256                               // pass-A blocks
#define EPB    ((N_EDGES + NBLKA - 1) / NBLKA)   // 12500
#define NB_BLK ((N_NODES + 255) / 256)

// new-path ws words: dinv N + rowstart N + rowend N + adj E + S max(32N,E)
//                    + cmat NBUCK*NBLKA + bt (NBUCK+1) + flag
#define NEW_WS_WORDS (3u*N_NODES + N_EDGES + 3200000u + NBUCK*NBLKA + NBUCK + 2u)
#define NEW_WS_BYTES (NEW_WS_WORDS * 4u)
// atomic fallback path (R4): 33N floats + flag
#define ATOMIC_WS_BYTES ((33u*N_NODES + 16u) * 4u)

// ---------------------------------------------------------------------------
// dtype probe: edge_index may be int32 or raw int64 (reference uses int64).
__global__ void k_detect_i64(const int* __restrict__ ei_words, int* __restrict__ flag) {
    if (blockIdx.x == 0 && threadIdx.x == 0) {
        int allzero = 1;
        for (int i = 0; i < 64; i++)
            if (ei_words[2 * i + 1] != 0) allzero = 0;
        *flag = allzero;  // 1 => int64 layout
    }
}

__device__ __forceinline__ unsigned load_idx(const int* p32, const long long* p64,
                                             int is64, int e) {
    return is64 ? (unsigned)(unsigned long long)p64[e] : (unsigned)p32[e];
}

// ---------------------------------------------------------------------------
// Pass A1: per-(bucket, block) edge counts. cmat[b*NBLKA + blk].
__global__ __launch_bounds__(256) void k_bcount(const int* __restrict__ dst32,
                                                const long long* __restrict__ dst64,
                                                const int* __restrict__ flag,
                                                int* __restrict__ cmat) {
    __shared__ int lc[NBUCK];
    int t = threadIdx.x, blk = blockIdx.x;
    for (int i = t; i < NBUCK; i += 256) lc[i] = 0;
    __syncthreads();
    int is64 = *flag;
    int e0 = blk * EPB;
    int e1 = e0 + EPB; if (e1 > N_EDGES) e1 = N_EDGES;
    for (int e = e0 + t; e < e1; e += 256) {
        unsigned d = load_idx(dst32, dst64, is64, e);
        if (d < N_NODES) atomicAdd(&lc[d >> 8], 1);
    }
    __syncthreads();
    for (int b = t; b < NBUCK; b += 256) cmat[b * NBLKA + blk] = lc[b];
}

// Pass A2: bucket totals bt[b] = sum_blk cmat[b][blk]
__global__ __launch_bounds__(256) void k_bsum(const int* __restrict__ cmat,
                                              int* __restrict__ bt) {
    int b = blockIdx.x, t = threadIdx.x;
    int v = cmat[b * NBLKA + t];
#pragma unroll
    for (int off = 32; off > 0; off >>= 1) v += __shfl_down(v, off, 64);
    __shared__ int s[4];
    if ((t & 63) == 0) s[t >> 6] = v;
    __syncthreads();
    if (t == 0) bt[b] = s[0] + s[1] + s[2] + s[3];
}

// Pass A3: exclusive scan of bt[0..NBUCK) in one block; bt[NBUCK] = total
__global__ __launch_bounds__(512) void k_btscan(int* __restrict__ bt) {
    __shared__ int s[512];
    int t = threadIdx.x;
    s[t] = (t < NBUCK) ? bt[t] : 0;
    __syncthreads();
    for (int off = 1; off < 512; off <<= 1) {
        int v = (t >= off) ? s[t - off] : 0;
        __syncthreads();
        s[t] += v;
        __syncthreads();
    }
    if (t < NBUCK) bt[t] = (t == 0) ? 0 : s[t - 1];
    if (t == 0) bt[NBUCK] = s[NBUCK - 1];
}

// Pass A4: cmat row b -> exclusive scan + bt[b] (absolute offsets), in place
__global__ __launch_bounds__(256) void k_boffs(int* __restrict__ cmat,
                                               const int* __restrict__ bt) {
    __shared__ int s[256];
    int b = blockIdx.x, t = threadIdx.x;
    int v0 = cmat[b * NBLKA + t];
    s[t] = v0;
    __syncthreads();
    for (int off = 1; off < 256; off <<= 1) {
        int v = (t >= off) ? s[t - off] : 0;
        __syncthreads();
        s[t] += v;
        __syncthreads();
    }
    cmat[b * NBLKA + t] = ((t == 0) ? 0 : s[t - 1]) + bt[b];
}

// Pass A5: scatter packed entries (dstLow<<17 | src) into bucket-major P.
// Each (bucket, block) region is written by exactly one block => L2-local,
// full-line writebacks.
__global__ __launch_bounds__(256) void k_bscatter(const int* __restrict__ src32,
                                                  const long long* __restrict__ src64,
                                                  const int* __restrict__ dst32,
                                                  const long long* __restrict__ dst64,
                                                  const int* __restrict__ flag,
                                                  const int* __restrict__ cmat,
                                                  int* __restrict__ P) {
    __shared__ int cur[NBUCK];
    int t = threadIdx.x, blk = blockIdx.x;
    for (int i = t; i < NBUCK; i += 256) cur[i] = cmat[i * NBLKA + blk];
    __syncthreads();
    int is64 = *flag;
    int e0 = blk * EPB;
    int e1 = e0 + EPB; if (e1 > N_EDGES) e1 = N_EDGES;
    for (int e = e0 + t; e < e1; e += 256) {
        unsigned d = load_idx(dst32, dst64, is64, e);
        if (d < N_NODES) {
            unsigned s = load_idx(src32, src64, is64, e);
            int pos = atomicAdd(&cur[d >> 8], 1);
            P[pos] = (int)(((d & 255u) << 17) | (s & 0x1FFFFu));
        }
    }
}

// Pass B: per-bucket CSR build. One block per bucket; all writes land in the
// bucket's own <=~32KB window (single XCD, coalesced writeback). Also emits
// rowstart/rowend/dinv -- replaces hist/dinv/global scans.
__global__ __launch_bounds__(256) void k_bbuild(const int* __restrict__ P,
                                                const int* __restrict__ bt,
                                                int* __restrict__ adj,
                                                int* __restrict__ rowstart,
                                                int* __restrict__ rowend,
                                                float* __restrict__ dinv) {
    __shared__ int cnt[NPB];
    __shared__ int s[NPB];
    int b = blockIdx.x, t = threadIdx.x;
    int bo = bt[b], be = bt[b + 1];
    cnt[t] = 0;
    __syncthreads();
    for (int i = bo + t; i < be; i += 256) atomicAdd(&cnt[P[i] >> 17], 1);
    __syncthreads();
    s[t] = cnt[t];
    __syncthreads();
    for (int off = 1; off < 256; off <<= 1) {
        int v = (t >= off) ? s[t - off] : 0;
        __syncthreads();
        s[t] += v;
        __syncthreads();
    }
    int ex = (t == 0) ? 0 : s[t - 1];
    int node = b * NPB + t;
    if (node < N_NODES) {
        rowstart[node] = bo + ex;
        rowend[node]   = bo + ex + cnt[t];
        dinv[node]     = rsqrtf((float)cnt[t] + 1.0f);
    }
    __syncthreads();
    s[t] = ex;  // cursors
    __syncthreads();
    for (int i = bo + t; i < be; i += 256) {
        int ent = P[i];
        int pos = bo + atomicAdd(&s[ent >> 17], 1);
        adj[pos] = ent & 0x1FFFF;
    }
}

// ---------------------------------------------------------------------------
// Layer-1 GEMM: xs[n][f] = dinv[n] * sum_k h[n][k] * W[k][f],  128 -> 16
__global__ __launch_bounds__(256) void k_gemm1(const float* __restrict__ h,
                                               const float* __restrict__ W,
                                               const float* __restrict__ dinv,
                                               float* __restrict__ xs,
                                               float* acc) {
    __shared__ float Wt[16 * 132];
    __shared__ float Hs[16 * 132];
    int tid = threadIdx.x;
    for (int i = tid; i < 2048; i += 256) {
        int k = i >> 4, f = i & 15;
        Wt[f * 132 + k] = W[i];
    }
    int nodeBase = blockIdx.x * 16;
    for (int i = tid; i < 512; i += 256) {
        int r = i >> 5, c = i & 31;
        float4 v = ((const float4*)(h + (size_t)(nodeBase + r) * 128))[c];
        *((float4*)&Hs[r * 132 + c * 4]) = v;
    }
    __syncthreads();
    int nl = tid >> 4;
    int f  = tid & 15;
    int n  = nodeBase + nl;
    const float* hr = &Hs[nl * 132];
    const float* wr = &Wt[f * 132];
    float s = 0.0f;
#pragma unroll
    for (int k = 0; k < 128; k++) s += hr[k] * wr[k];
    s *= dinv[n];
    xs[n * 16 + f]  = s;
    acc[n * 16 + f] = s;
}

template <int FI, int FO>
__global__ __launch_bounds__(256) void k_gemm_small(const float* __restrict__ x,
                                                    const float* __restrict__ W,
                                                    const float* __restrict__ dinv,
                                                    float* __restrict__ xs,
                                                    float* acc) {
    int i = blockIdx.x * 256 + threadIdx.x;
    if (i >= N_NODES * FO) return;
    int n = i / FO, f = i % FO;
    float s = 0.0f;
#pragma unroll
    for (int k = 0; k < FI; k++) s += x[n * FI + k] * W[k * FO + f];
    s *= dinv[n];
    xs[i] = s;
    acc[i] = s;
}

// ---------------------------------------------------------------------------
// Pull aggregation, fused finish:  out[n][f] = tanh(dinv[n]*(xs[n][f] +
//   sum_{src in row(n)} xs[src][f]) + b[f]).  NL lanes/node, R=NL/F slots.
template <int F, int NL>
__global__ __launch_bounds__(256) void k_pull(const float* __restrict__ xs,
                                              const int* __restrict__ adj,
                                              const int* __restrict__ rowstart,
                                              const int* __restrict__ rowend,
                                              const float* __restrict__ dinv,
                                              const float* __restrict__ b,
                                              float* __restrict__ out) {
    constexpr int R = NL / F;
    int t = threadIdx.x;
    int g = t / NL, q = t % NL;
    int f = q % F,  k = q / F;
    int n = blockIdx.x * (256 / NL) + g;
    if (n >= N_NODES) return;
    int s0 = rowstart[n], e0 = rowend[n];
    float acc = 0.0f;
    for (int j = s0 + k; j < e0; j += R)
        acc += xs[adj[j] * F + f];
#pragma unroll
    for (int off = NL / 2; off >= F; off >>= 1)
        acc += __shfl_xor(acc, off, 64);
    if (k == 0) {
        acc += xs[n * F + f];  // self loop
        out[n * F + f] = tanhf(dinv[n] * acc + b[f]);
    }
}

// Layer-3 pull (F=2, NL=8, R=4) fused with h3 write and 2->8 classifier.
__global__ __launch_bounds__(256) void k_pull_final(const float* __restrict__ xs,
                                                    const int* __restrict__ adj,
                                                    const int* __restrict__ rowstart,
                                                    const int* __restrict__ rowend,
                                                    const float* __restrict__ dinv,
                                                    const float* __restrict__ b3,
                                                    const float* __restrict__ Wc,
                                                    const float* __restrict__ bc,
                                                    float* __restrict__ out,
                                                    float* __restrict__ h3out) {
    const int NL = 8;
    int t = threadIdx.x;
    int g = t / NL, q = t % NL;
    int f = q & 1, k = q >> 1;
    int n = blockIdx.x * (256 / NL) + g;
    if (n >= N_NODES) return;
    int s0 = rowstart[n], e0 = rowend[n];
    float acc = 0.0f;
    for (int j = s0 + k; j < e0; j += 4)
        acc += xs[adj[j] * 2 + f];
    acc += __shfl_xor(acc, 4, 64);
    acc += __shfl_xor(acc, 2, 64);
    float a = 0.0f;
    if (q < 2) {
        acc += xs[n * 2 + f];
        a = tanhf(dinv[n] * acc + b3[f]);
        h3out[2 * n + f] = a;
    }
    int wl = t & 63, gb = wl & ~7;
    float a0 = __shfl(a, gb, 64);
    float a1 = __shfl(a, gb + 1, 64);
    out[8 * n + q] = a0 * Wc[q] + a1 * Wc[8 + q] + bc[q];
}

// ---------------------------------------------------------------------------
// Atomic fallback (R4 pipeline) — only if ws is unexpectedly small
template <int F>
__global__ __launch_bounds__(256) void k_scatter(const int* __restrict__ src32,
                                                 const long long* __restrict__ src64,
                                                 const int* __restrict__ dst32,
                                                 const long long* __restrict__ dst64,
                                                 const int* __restrict__ flag,
                                                 const float* __restrict__ xs,
                                                 float* __restrict__ acc) {
    long long gid = (long long)blockIdx.x * 256 + threadIdx.x;
    int e = (int)(gid / F), f = (int)(gid % F);
    if (e < N_EDGES) {
        int is64 = *flag;
        unsigned s = load_idx(src32, src64, is64, e);
        unsigned d = load_idx(dst32, dst64, is64, e);
        if (s < N_NODES && d < N_NODES)
            atomicAdd(&acc[d * F + f], xs[s * F + f]);
    }
}
__global__ __launch_bounds__(256) void k_deg_init(float* __restrict__ deg) {
    int i = blockIdx.x * 256 + threadIdx.x;
    if (i < N_NODES) deg[i] = 1.0f;
}
__global__ __launch_bounds__(256) void k_deg_count(const int* __restrict__ dst32,
                                                   const long long* __restrict__ dst64,
                                                   const int* __restrict__ flag,
                                                   float* __restrict__ deg) {
    int e = blockIdx.x * 256 + threadIdx.x;
    if (e < N_EDGES) {
        unsigned d = load_idx(dst32, dst64, *flag, e);
        if (d < N_NODES) atomicAdd(&deg[d], 1.0f);
    }
}
__global__ __launch_bounds__(256) void k_rsqrt(float* __restrict__ deg) {
    int i = blockIdx.x * 256 + threadIdx.x;
    if (i < N_NODES) deg[i] = rsqrtf(deg[i]);
}
template <int F>
__global__ __launch_bounds__(256) void k_finish(const float* __restrict__ acc,
                                                const float* __restrict__ dinv,
                                                const float* __restrict__ b,
                                                float* __restrict__ out) {
    int i = blockIdx.x * 256 + threadIdx.x;
    if (i >= N_NODES * F) return;
    int n = i / F, f = i % F;
    out[i] = tanhf(dinv[n] * acc[i] + b[f]);
}
__global__ __launch_bounds__(256) void k_final(const float* __restrict__ acc3,
                                               const float* __restrict__ dinv,
                                               const float* __restrict__ b3,
                                               const float* __restrict__ Wc,
                                               const float* __restrict__ bc,
                                               float* __restrict__ out,
                                               float* __restrict__ h3out) {
    int n = blockIdx.x * 256 + threadIdx.x;
    if (n >= N_NODES) return;
    float di = dinv[n];
    float a0 = tanhf(di * acc3[2 * n + 0] + b3[0]);
    float a1 = tanhf(di * acc3[2 * n + 1] + b3[1]);
    h3out[2 * n + 0] = a0;
    h3out[2 * n + 1] = a1;
#pragma unroll
    for (int c = 0; c < 8; c++)
        out[8 * n + c] = a0 * Wc[c] + a1 * Wc[8 + c] + bc[c];
}
__global__ __launch_bounds__(256) void k_zero_out(float* __restrict__ out, int n) {
    int i = blockIdx.x * 256 + threadIdx.x;
    if (i < n) out[i] = 0.0f;
}

// ---------------------------------------------------------------------------
extern "C" void kernel_launch(void* const* d_in, const int* in_sizes, int n_in,
                              void* d_out, int out_size, void* d_ws, size_t ws_size,
                              hipStream_t stream) {
    float* out = (float*)d_out;
    const float* h   = (const float*)d_in[0];
    const void*  ei  = d_in[1];
    const float* W1  = (const float*)d_in[2];
    const float* b1  = (const float*)d_in[3];
    const float* W2  = (const float*)d_in[4];
    const float* b2  = (const float*)d_in[5];
    const float* W3  = (const float*)d_in[6];
    const float* b3  = (const float*)d_in[7];
    const float* Wc  = (const float*)d_in[8];
    const float* bc  = (const float*)d_in[9];

    const int*       src32 = (const int*)ei;
    const int*       dst32 = src32 + N_EDGES;
    const long long* src64 = (const long long*)ei;
    const long long* dst64 = src64 + N_EDGES;

    float* h3out = out + 8 * N_NODES;
    const int NB_E = (N_EDGES + 255) / 256;

    if (d_ws != nullptr && ws_size >= NEW_WS_BYTES) {
        // ---------------- multisplit CSR + pull path ----------------
        float* dinv    = (float*)d_ws;               // N
        int* rowstart  = (int*)(dinv + N_NODES);     // N
        int* rowend    = rowstart + N_NODES;         // N
        int* adj       = rowend + N_NODES;           // E
        int* S         = adj + N_EDGES;              // 32N == E words, shared
        float* xs      = (float*)S;                  // 16N (after build)
        float* hbuf    = xs + 16 * N_NODES;          // 16N
        int* P         = S;                          // E (during build)
        int* cmat      = S + 3200000;                // NBUCK*NBLKA
        int* bt        = cmat + NBUCK * NBLKA;       // NBUCK+1
        int* flag      = bt + NBUCK + 1;             // 1

        k_detect_i64<<<1, 64, 0, stream>>>(src32, flag);
        k_bcount<<<NBLKA, 256, 0, stream>>>(dst32, dst64, flag, cmat);
        k_bsum<<<NBUCK, 256, 0, stream>>>(cmat, bt);
        k_btscan<<<1, 512, 0, stream>>>(bt);
        k_boffs<<<NBUCK, 256, 0, stream>>>(cmat, bt);
        k_bscatter<<<NBLKA, 256, 0, stream>>>(src32, src64, dst32, dst64, flag, cmat, P);
        k_bbuild<<<NBUCK, 256, 0, stream>>>(P, bt, adj, rowstart, rowend, dinv);

        // layer 1: 128 -> 16   (xs overwrites P — P is dead after k_bbuild)
        k_gemm1<<<N_NODES / 16, 256, 0, stream>>>(h, W1, dinv, xs, xs);
        k_pull<16, 64><<<(N_NODES * 64 + 255) / 256, 256, 0, stream>>>(
            xs, adj, rowstart, rowend, dinv, b1, hbuf);
        // layer 2: 16 -> 4
        k_gemm_small<16, 4><<<(N_NODES * 4 + 255) / 256, 256, 0, stream>>>(hbuf, W2, dinv, xs, xs);
        k_pull<4, 16><<<(N_NODES * 16 + 255) / 256, 256, 0, stream>>>(
            xs, adj, rowstart, rowend, dinv, b2, hbuf);
        // layer 3: 4 -> 2, fused classifier
        k_gemm_small<4, 2><<<(N_NODES * 2 + 255) / 256, 256, 0, stream>>>(hbuf, W3, dinv, xs, xs);
        k_pull_final<<<(N_NODES * 8 + 255) / 256, 256, 0, stream>>>(
            xs, adj, rowstart, rowend, dinv, b3, Wc, bc, out, h3out);
        return;
    }

    if (d_ws != nullptr && ws_size >= ATOMIC_WS_BYTES) {
        // ---------------- atomic fallback (R4) ----------------
        float* ws   = (float*)d_ws;
        float* dinv = ws;
        float* bufA = dinv + N_NODES;
        float* bufB = bufA + 16 * N_NODES;
        int*   flag = (int*)(bufB + 16 * N_NODES);
        float* xs1 = bufA, *acc1 = bufB, *h1 = bufA;
        float* xs2 = bufB, *acc2 = bufB + 4 * N_NODES, *h2 = bufA;
        float* xs3 = bufB, *acc3 = bufB + 2 * N_NODES;

        k_detect_i64<<<1, 64, 0, stream>>>(src32, flag);
        k_deg_init<<<NB_BLK, 256, 0, stream>>>(dinv);
        k_deg_count<<<NB_E, 256, 0, stream>>>(dst32, dst64, flag, dinv);
        k_rsqrt<<<NB_BLK, 256, 0, stream>>>(dinv);
        k_gemm1<<<N_NODES / 16, 256, 0, stream>>>(h, W1, dinv, xs1, acc1);
        k_scatter<16><<<(int)(((long long)N_EDGES * 16 + 255) / 256), 256, 0, stream>>>(
            src32, src64, dst32, dst64, flag, xs1, acc1);
        k_finish<16><<<(N_NODES * 16 + 255) / 256, 256, 0, stream>>>(acc1, dinv, b1, h1);
        k_gemm_small<16, 4><<<(N_NODES * 4 + 255) / 256, 256, 0, stream>>>(h1, W2, dinv, xs2, acc2);
        k_scatter<4><<<(int)(((long long)N_EDGES * 4 + 255) / 256), 256, 0, stream>>>(
            src32, src64, dst32, dst64, flag, xs2, acc2);
        k_finish<4><<<(N_NODES * 4 + 255) / 256, 256, 0, stream>>>(acc2, dinv, b2, h2);
        k_gemm_small<4, 2><<<(N_NODES * 2 + 255) / 256, 256, 0, stream>>>(h2, W3, dinv, xs3, acc3);
        k_scatter<2><<<(int)(((long long)N_EDGES * 2 + 255) / 256), 256, 0, stream>>>(
            src32, src64, dst32, dst64, flag, xs3, acc3);
        k_final<<<NB_BLK, 256, 0, stream>>>(acc3, dinv, b3, Wc, bc, out, h3out);
        return;
    }

    k_zero_out<<<(out_size + 255) / 256, 256, 0, stream>>>(out, out_size);
}